// Round 11
// baseline (18.565 us; speedup 1.0000x reference)
//
#include <hip/hip_runtime.h>
#include <hip/hip_bf16.h>

#define S_IMG    128
#define KTOP     16
#define RAD2     (0.02f*0.02f)
#define INV_R2   (1.0f/RAD2)
#define RADF     0.02f
#define ZNEARF   1.0f
#define FOCALF   1.7320508075688772f   // 1/tan(30 deg)
#define NTILE    128                   // 16x8-px tiles: 8 across x 16 down
#define TPB      1024                  // 16 waves; 8 sub-lanes per pixel
#define SUBS     8
#define CAP      512                   // worst central 16x8 tile ~190 expected
#define KSENT    0xFFFFFFFFu

__global__ __launch_bounds__(TPB) void render_tile16(
    const float* __restrict__ points,
    const float* __restrict__ eye,
    const float* __restrict__ colors,
    float* __restrict__ out,
    int N)
{
    __shared__ float s_cx[CAP];                          // unsorted candidates
    __shared__ float s_cy[CAP];
    __shared__ __align__(16) unsigned s_key[CAP + 8];    // (z bits & ~2047) | idx
    __shared__ __align__(16) float2   s_sxy [CAP + 32];  // z-sorted (x,y) + sentinels
    __shared__ __align__(16) float4   s_scol[CAP + 32];  // z-sorted (r,g,b,-) + zeros
    __shared__ int s_cnt;

    const int tid  = threadIdx.x;
    const int lane = tid & 63;
    const int blk  = blockIdx.x;
    const int b    = blk >> 7;                 // NTILE == 128
    const int t    = blk & 127;
    const int ty   = t >> 3;                   // tile row (0..15), 8 px tall
    const int tx   = t & 7;                    // tile col (0..7), 16 px wide

    // ---- camera basis (PyTorch3D look_at: at=origin, up=+y; R cols = x,y,z) ----
    const float ex = eye[b*3+0], ey = eye[b*3+1], ez = eye[b*3+2];
    const float zinv = 1.0f / sqrtf(ex*ex + ey*ey + ez*ez);
    const float zax = -ex*zinv, zay = -ey*zinv, zaz = -ez*zinv;
    const float xinv = 1.0f / sqrtf(zaz*zaz + zax*zax);
    const float xax = zaz*xinv, xaz = -zax*xinv;        // x-axis y-component == 0
    const float yax = zay*xaz;
    const float yay = zaz*xax - zax*xaz;
    const float yaz = -zay*xax;

    // ---- tile bbox in NDC (pixel centers) + radius pad ----
    const float cx = 1.0f - (float)(2*(tx*16) + 16) / S_IMG;
    const float cy = 1.0f - (float)(2*(ty*8)  + 8)  / S_IMG;
    const float hx = 15.0f / S_IMG + RADF + 1e-6f;
    const float hy =  7.0f / S_IMG + RADF + 1e-6f;

    if (tid == 0) s_cnt = 0;
    __syncthreads();

    // ---- phase 1: project + cull; 4 pts via 3 coalesced float4 loads;
    //      wave-aggregated LDS atomic ----
    const float4* pq = reinterpret_cast<const float4*>(points + b*N*3);
    const int nquad = N >> 2;
    for (int qd = tid; qd < nquad; qd += TPB) {
        float4 A  = pq[3*qd+0];
        float4 Bv = pq[3*qd+1];
        float4 C  = pq[3*qd+2];
        float qx[4] = {A.x, A.w, Bv.z, C.y};
        float qy[4] = {A.y, Bv.x, Bv.w, C.z};
        float qz[4] = {A.z, Bv.y, C.x, C.w};
        #pragma unroll
        for (int u = 0; u < 4; ++u) {
            float wx = qx[u] - ex, wy = qy[u] - ey, wz = qz[u] - ez;
            float cz = wx*zax + wy*zay + wz*zaz;
            float xn = 0.f, yn = 0.f;
            bool keep = (cz > ZNEARF);
            if (keep) {
                float inv = FOCALF / cz;
                xn = (wx*xax + wz*xaz) * inv;
                yn = (wx*yax + wy*yay + wz*yaz) * inv;
                keep = (fabsf(xn - cx) <= hx) && (fabsf(yn - cy) <= hy);
            }
            unsigned long long act = __ballot(keep);
            if (act) {
                int lead = (int)__ffsll(act) - 1;
                int base = 0;
                if (lane == lead) base = atomicAdd(&s_cnt, __popcll(act));
                base = __shfl(base, lead, 64);
                if (keep) {
                    int slot = base + __popcll(act & ((1ull << lane) - 1ull));
                    if (slot < CAP) {
                        s_cx [slot] = xn;
                        s_cy [slot] = yn;
                        s_key[slot] = (__float_as_uint(cz) & ~2047u)
                                    | (unsigned)(4*qd + u);
                    }
                }
            }
        }
    }
    __syncthreads();
    int M = s_cnt; if (M > CAP) M = CAP;

    // ---- sentinel pads ----
    if (tid < 32) {
        if (tid < 8) s_key[M + tid] = KSENT;
        s_sxy [M + tid] = make_float2(1.0e9f, 1.0e9f);   // never hits
        s_scol[M + tid] = make_float4(0.f, 0.f, 0.f, 0.f);
    }
    __syncthreads();

    // ---- phase 2: rank-sort (1 candidate/thread); gather colors ----
    const float* cols = colors + b*N*3;
    if (tid < M) {
        const unsigned mk = s_key[tid];
        const float ux = s_cx[tid], uy = s_cy[tid];
        const uint4* k4 = reinterpret_cast<const uint4*>(s_key);
        const int nb = (M + 7) >> 3;
        int rank = 0;
        for (int q = 0; q < nb; ++q) {                   // broadcast b128 reads
            uint4 a  = k4[2*q];
            uint4 bb = k4[2*q+1];
            rank += (int)(a.x <mk) + (int)(a.y <mk) + (int)(a.z <mk) + (int)(a.w <mk)
                  + (int)(bb.x<mk) + (int)(bb.y<mk) + (int)(bb.z<mk) + (int)(bb.w<mk);
        }
        const int pi = (int)(mk & 2047u);
        s_sxy [rank] = make_float2(ux, uy);
        s_scol[rank] = make_float4(cols[3*pi+0], cols[3*pi+1], cols[3*pi+2], 0.0f);
    }
    __syncthreads();

    // ---- phase 3: 8 subs/pixel scan z-contiguous segments, then merge ----
    const int sub = tid & (SUBS-1);            // subs are adjacent lanes
    const int p   = tid >> 3;                  // pixel within tile (0..127)
    const int row = ty*8  + (p >> 4);
    const int col = tx*16 + (p & 15);
    const float pxc = 1.0f - (2.0f*col + 1.0f) / S_IMG;
    const float pyc = 1.0f - (2.0f*row + 1.0f) / S_IMG;

    const int L    = 4 * ((M + 31) >> 5);      // per-sub segment (multiple of 4)
    const int base = sub * L;                  // max read idx 8L-1 <= M+31

    const float4* xy4 = reinterpret_cast<const float4*>(s_sxy);
    float T = 1.0f, r = 0.0f, g = 0.0f, bl = 0.0f;
    int hits = 0;
    for (int i = 0; i < L; i += 4) {
        const int ii = base + i;
        float4 u   = xy4[(ii >> 1) + 0];
        float4 v   = xy4[(ii >> 1) + 1];
        float4 c0v = s_scol[ii + 0];
        float4 c1v = s_scol[ii + 1];
        float4 c2v = s_scol[ii + 2];
        float4 c3v = s_scol[ii + 3];
        float dx, dy, d2, a, w; bool h;

        dx = pxc - u.x; dy = pyc - u.y; d2 = dx*dx + dy*dy;
        h = (d2 < RAD2); hits += h ? 1 : 0;
        a = h ? 1.0f - d2 * INV_R2 : 0.0f;
        w = a * T; r += w*c0v.x; g += w*c0v.y; bl += w*c0v.z; T -= T*a;

        dx = pxc - u.z; dy = pyc - u.w; d2 = dx*dx + dy*dy;
        h = (d2 < RAD2); hits += h ? 1 : 0;
        a = h ? 1.0f - d2 * INV_R2 : 0.0f;
        w = a * T; r += w*c1v.x; g += w*c1v.y; bl += w*c1v.z; T -= T*a;

        dx = pxc - v.x; dy = pyc - v.y; d2 = dx*dx + dy*dy;
        h = (d2 < RAD2); hits += h ? 1 : 0;
        a = h ? 1.0f - d2 * INV_R2 : 0.0f;
        w = a * T; r += w*c2v.x; g += w*c2v.y; bl += w*c2v.z; T -= T*a;

        dx = pxc - v.z; dy = pyc - v.w; d2 = dx*dx + dy*dy;
        h = (d2 < RAD2); hits += h ? 1 : 0;
        a = h ? 1.0f - d2 * INV_R2 : 0.0f;
        w = a * T; r += w*c3v.x; g += w*c3v.y; bl += w*c3v.z; T -= T*a;
    }

    // ordered over-compose across the 8 subs (associative, non-commutative)
    #pragma unroll
    for (int mx = 1; mx <= 4; mx <<= 1) {
        float pr = __shfl_xor(r,  mx, 64);
        float pg = __shfl_xor(g,  mx, 64);
        float pb = __shfl_xor(bl, mx, 64);
        float pT = __shfl_xor(T,  mx, 64);
        int   ph = __shfl_xor(hits, mx, 64);
        const bool lower = (sub & mx) == 0;    // my segment precedes partner's
        r  = lower ? r  + T*pr : pr + pT*r;
        g  = lower ? g  + T*pg : pg + pT*g;
        bl = lower ? bl + T*pb : pb + pT*bl;
        T  = lower ? T*pT      : pT*T;
        hits += ph;
    }

    if (sub == 0) {
        if (hits > KTOP) {                     // exact K-cap fallback (≈ never)
            T = 1.0f; r = 0.0f; g = 0.0f; bl = 0.0f;
            int hh = 0;
            for (int i = 0; i < M && hh < KTOP; ++i) {
                float2 xy = s_sxy[i];
                float dx = pxc - xy.x, dy = pyc - xy.y;
                float d2 = dx*dx + dy*dy;
                if (d2 < RAD2) {
                    float4 cc = s_scol[i];
                    float a = 1.0f - d2 * INV_R2;
                    float w = a * T;
                    r += w*cc.x; g += w*cc.y; bl += w*cc.z;
                    T -= T*a; ++hh;
                }
            }
        }
        const int gpix = b * (S_IMG*S_IMG) + row * S_IMG + col;
        float* o = out + (size_t)gpix * 3;
        o[0] = r; o[1] = g; o[2] = bl;
    }
}

extern "C" void kernel_launch(void* const* d_in, const int* in_sizes, int n_in,
                              void* d_out, int out_size, void* d_ws, size_t ws_size,
                              hipStream_t stream)
{
    const float* points = (const float*)d_in[0];
    const float* eye    = (const float*)d_in[1];
    const float* colors = (const float*)d_in[2];
    float* out = (float*)d_out;

    const int B = in_sizes[1] / 3;              // eye is [B,3]
    const int N = in_sizes[0] / (3 * B);        // points is [B,N,3] (N <= 2048)

    render_tile16<<<B * NTILE, TPB, 0, stream>>>(points, eye, colors, out, N);
}

// Round 12
// 14.259 us; speedup vs baseline: 1.3020x; 1.3020x over previous
//
#include <hip/hip_runtime.h>
#include <hip/hip_bf16.h>

#define S_IMG    128
#define KTOP     16
#define RAD2     (0.02f*0.02f)
#define INV_R2   (1.0f/RAD2)
#define RADF     0.02f
#define ZNEARF   1.0f
#define FOCALF   1.7320508075688772f   // 1/tan(30 deg)
#define TPI      16                    // 8x8-pixel tiles, 16 per axis
#define NTILE    (TPI*TPI)             // 256 tiles per image
#define TPB      512                   // 8 waves; 8 sub-lanes per pixel
#define SUBS     8
#define CAP      256                   // worst central 8x8 tile ~150 expected
#define KSENT    0xFFFFFFFFu

__global__ __launch_bounds__(TPB) void render_tile8(
    const float* __restrict__ points,
    const float* __restrict__ eye,
    const float* __restrict__ colors,
    float* __restrict__ out,
    int N)
{
    __shared__ float s_cx[CAP];                          // unsorted candidate x
    __shared__ float s_cy[CAP];                          // unsorted candidate y
    __shared__ __align__(16) float4   s_ucol[CAP];       // unsorted colors (P1 gather)
    __shared__ __align__(16) unsigned s_key [CAP + 8];   // (z bits & ~2047) | idx
    __shared__ __align__(16) float2   s_sxy [CAP + 32];  // z-sorted (x,y)
    __shared__ __align__(16) float4   s_scol[CAP + 32];  // z-sorted (r,g,b,-)
    __shared__ int s_cnt;

    const int tid  = threadIdx.x;
    const int lane = tid & 63;
    const int blk  = blockIdx.x;
    const int b    = blk >> 8;                 // NTILE == 256
    const int t    = blk & 255;
    const int ty   = t >> 4, tx = t & 15;

    // ---- init: zero counter + pre-fill ALL sentinel regions (kills pad phase) ----
    for (int i = tid; i < CAP + 32; i += TPB) {
        if (i < CAP + 8) s_key[i] = KSENT;
        s_sxy [i] = make_float2(1.0e9f, 1.0e9f);         // never hits
        s_scol[i] = make_float4(0.f, 0.f, 0.f, 0.f);     // contributes nothing
    }
    if (tid == 0) s_cnt = 0;

    // ---- camera basis (PyTorch3D look_at: at=origin, up=+y; R cols = x,y,z) ----
    const float ex = eye[b*3+0], ey = eye[b*3+1], ez = eye[b*3+2];
    const float zinv = 1.0f / sqrtf(ex*ex + ey*ey + ez*ez);
    const float zax = -ex*zinv, zay = -ey*zinv, zaz = -ez*zinv;
    const float xinv = 1.0f / sqrtf(zaz*zaz + zax*zax);
    const float xax = zaz*xinv, xaz = -zax*xinv;        // x-axis y-component == 0
    const float yax = zay*xaz;
    const float yay = zaz*xax - zax*xaz;
    const float yaz = -zay*xax;

    // ---- tile bbox in NDC (pixel centers) + radius pad ----
    const float cx = 1.0f - (float)(2*(tx*8) + 8) / S_IMG;
    const float cy = 1.0f - (float)(2*(ty*8) + 8) / S_IMG;
    const float hx = 7.0f / S_IMG + RADF + 1e-6f;
    const float hy = 7.0f / S_IMG + RADF + 1e-6f;

    __syncthreads();

    // ---- phase 1: project + cull + immediate color gather (latency overlapped);
    //      4 pts via 3 coalesced float4 loads; wave-aggregated LDS atomic ----
    const float*  cols = colors + b*N*3;
    const float4* pq = reinterpret_cast<const float4*>(points + b*N*3);
    const int nquad = N >> 2;
    for (int qd = tid; qd < nquad; qd += TPB) {
        float4 A  = pq[3*qd+0];
        float4 Bv = pq[3*qd+1];
        float4 C  = pq[3*qd+2];
        float qx[4] = {A.x, A.w, Bv.z, C.y};
        float qy[4] = {A.y, Bv.x, Bv.w, C.z};
        float qz[4] = {A.z, Bv.y, C.x, C.w};
        #pragma unroll
        for (int u = 0; u < 4; ++u) {
            float wx = qx[u] - ex, wy = qy[u] - ey, wz = qz[u] - ez;
            float cz = wx*zax + wy*zay + wz*zaz;
            float xn = 0.f, yn = 0.f;
            bool keep = (cz > ZNEARF);
            if (keep) {
                float inv = FOCALF / cz;
                xn = (wx*xax + wz*xaz) * inv;
                yn = (wx*yax + wy*yay + wz*yaz) * inv;
                keep = (fabsf(xn - cx) <= hx) && (fabsf(yn - cy) <= hy);
            }
            unsigned long long act = __ballot(keep);
            if (act) {
                int lead = (int)__ffsll(act) - 1;
                int base = 0;
                if (lane == lead) base = atomicAdd(&s_cnt, __popcll(act));
                base = __shfl(base, lead, 64);
                if (keep) {
                    int slot = base + __popcll(act & ((1ull << lane) - 1ull));
                    if (slot < CAP) {
                        const int pi = 4*qd + u;
                        s_cx  [slot] = xn;
                        s_cy  [slot] = yn;
                        s_key [slot] = (__float_as_uint(cz) & ~2047u) | (unsigned)pi;
                        s_ucol[slot] = make_float4(cols[3*pi+0], cols[3*pi+1],
                                                   cols[3*pi+2], 0.0f);
                    }
                }
            }
        }
    }
    __syncthreads();
    int M = s_cnt; if (M > CAP) M = CAP;

    // ---- phase 2: rank-sort (1 candidate/thread), pure LDS permute ----
    if (tid < M) {
        const unsigned mk = s_key[tid];
        const uint4* k4 = reinterpret_cast<const uint4*>(s_key);
        const int nb = (M + 7) >> 3;
        int rank = 0;
        for (int q = 0; q < nb; ++q) {                   // broadcast b128 reads
            uint4 a  = k4[2*q];
            uint4 bb = k4[2*q+1];
            rank += (int)(a.x <mk) + (int)(a.y <mk) + (int)(a.z <mk) + (int)(a.w <mk)
                  + (int)(bb.x<mk) + (int)(bb.y<mk) + (int)(bb.z<mk) + (int)(bb.w<mk);
        }
        s_sxy [rank] = make_float2(s_cx[tid], s_cy[tid]);
        s_scol[rank] = s_ucol[tid];
    }
    __syncthreads();

    // ---- phase 3: 8 subs/pixel scan z-contiguous segments, then merge ----
    const int sub = tid & (SUBS-1);            // subs are adjacent lanes
    const int p   = tid >> 3;                  // pixel within tile (0..63)
    const int row = ty*8 + (p >> 3);
    const int col = tx*8 + (p & 7);
    const float pxc = 1.0f - (2.0f*col + 1.0f) / S_IMG;
    const float pyc = 1.0f - (2.0f*row + 1.0f) / S_IMG;

    const int L    = 4 * ((M + 31) >> 5);      // per-sub segment (multiple of 4)
    const int base = sub * L;                  // max read idx 8L-1 <= M+31

    const float4* xy4 = reinterpret_cast<const float4*>(s_sxy);
    float T = 1.0f, r = 0.0f, g = 0.0f, bl = 0.0f;
    int hits = 0;
    for (int i = 0; i < L; i += 4) {
        const int ii = base + i;
        float4 u   = xy4[(ii >> 1) + 0];
        float4 v   = xy4[(ii >> 1) + 1];
        float4 c0v = s_scol[ii + 0];
        float4 c1v = s_scol[ii + 1];
        float4 c2v = s_scol[ii + 2];
        float4 c3v = s_scol[ii + 3];
        float dx, dy, d2, a, w; bool h;

        dx = pxc - u.x; dy = pyc - u.y; d2 = dx*dx + dy*dy;
        h = (d2 < RAD2); hits += h ? 1 : 0;
        a = h ? 1.0f - d2 * INV_R2 : 0.0f;
        w = a * T; r += w*c0v.x; g += w*c0v.y; bl += w*c0v.z; T -= T*a;

        dx = pxc - u.z; dy = pyc - u.w; d2 = dx*dx + dy*dy;
        h = (d2 < RAD2); hits += h ? 1 : 0;
        a = h ? 1.0f - d2 * INV_R2 : 0.0f;
        w = a * T; r += w*c1v.x; g += w*c1v.y; bl += w*c1v.z; T -= T*a;

        dx = pxc - v.x; dy = pyc - v.y; d2 = dx*dx + dy*dy;
        h = (d2 < RAD2); hits += h ? 1 : 0;
        a = h ? 1.0f - d2 * INV_R2 : 0.0f;
        w = a * T; r += w*c2v.x; g += w*c2v.y; bl += w*c2v.z; T -= T*a;

        dx = pxc - v.z; dy = pyc - v.w; d2 = dx*dx + dy*dy;
        h = (d2 < RAD2); hits += h ? 1 : 0;
        a = h ? 1.0f - d2 * INV_R2 : 0.0f;
        w = a * T; r += w*c3v.x; g += w*c3v.y; bl += w*c3v.z; T -= T*a;
    }

    // ordered over-compose across the 8 subs (associative, non-commutative)
    #pragma unroll
    for (int mx = 1; mx <= 4; mx <<= 1) {
        float pr = __shfl_xor(r,  mx, 64);
        float pg = __shfl_xor(g,  mx, 64);
        float pb = __shfl_xor(bl, mx, 64);
        float pT = __shfl_xor(T,  mx, 64);
        int   ph = __shfl_xor(hits, mx, 64);
        const bool lower = (sub & mx) == 0;    // my segment precedes partner's
        r  = lower ? r  + T*pr : pr + pT*r;
        g  = lower ? g  + T*pg : pg + pT*g;
        bl = lower ? bl + T*pb : pb + pT*bl;
        T  = lower ? T*pT      : pT*T;
        hits += ph;
    }

    if (sub == 0) {
        if (hits > KTOP) {                     // exact K-cap fallback (≈ never)
            T = 1.0f; r = 0.0f; g = 0.0f; bl = 0.0f;
            int hh = 0;
            for (int i = 0; i < M && hh < KTOP; ++i) {
                float2 xy = s_sxy[i];
                float dx = pxc - xy.x, dy = pyc - xy.y;
                float d2 = dx*dx + dy*dy;
                if (d2 < RAD2) {
                    float4 cc = s_scol[i];
                    float a = 1.0f - d2 * INV_R2;
                    float w = a * T;
                    r += w*cc.x; g += w*cc.y; bl += w*cc.z;
                    T -= T*a; ++hh;
                }
            }
        }
        const int gpix = b * (S_IMG*S_IMG) + row * S_IMG + col;
        float* o = out + (size_t)gpix * 3;
        o[0] = r; o[1] = g; o[2] = bl;
    }
}

extern "C" void kernel_launch(void* const* d_in, const int* in_sizes, int n_in,
                              void* d_out, int out_size, void* d_ws, size_t ws_size,
                              hipStream_t stream)
{
    const float* points = (const float*)d_in[0];
    const float* eye    = (const float*)d_in[1];
    const float* colors = (const float*)d_in[2];
    float* out = (float*)d_out;

    const int B = in_sizes[1] / 3;              // eye is [B,3]
    const int N = in_sizes[0] / (3 * B);        // points is [B,N,3] (N <= 2048)

    render_tile8<<<B * NTILE, TPB, 0, stream>>>(points, eye, colors, out, N);
}